// Round 5
// baseline (62.667 us; speedup 1.0000x reference)
//
#include <hip/hip_runtime.h>
#include <math.h>

// Inter-prediction: 21x21 search, 4x4 blocks, softmax(-100*meanAbsDiff).
//
// R8: paired-tile blocks. Each WG (256 thr, 4 waves) processes TWO
// horizontally adjacent 2x2-block tiles (8x16 px output) from ONE combined
// 28x36 im2 window (the two 28x28 windows overlap by 20 cols):
//  - staging 504 float2 vs 784 for same output area (-36%), one barrier;
//  - grid 1024 = 4 blocks/CU -> single fully-resident occupancy round
//    (was 2 rounds of 2048 blocks): no second cold-start, better overlap;
//  - tile B reuses 2 of tile A's 10 w2 register columns (16 vs 20 ds_read2);
//  - tile B's a2 (im1) loads issued mid-tile-A (a2 dead after SAD) to hide
//    global latency under phase2+reduces.
// Compute/reduce code is R7-verbatim (DPP xor1/xor2/xor8 + shfl 4/16/32,
// proven): swizzles 9/thread, rest on VALU.
// Carried: col-major stride-29 window, float2 staging w/ interior fast path,
// __launch_bounds__(256,4).

typedef float v2f __attribute__((ext_vector_type(2)));

#define HH 256
#define WW 256
#define PAD 10
#define NR 28               // window rows
#define NCW 36              // combined window cols (28 + 8)
#define CSTR 29             // odd per-column stride (floats)
#define LDSN (NCW * CSTR)   // 1044 floats = 4176 B

// Exact-xor lane exchange on the VALU (no LDS pipe, no lgkmcnt).
// CTRL: 0xB1 = xor1, 0x4E = xor2, 0x128 = xor8 (ROW_ROR:8 on a 16-ring).
template <int CTRL>
__device__ __forceinline__ float dppf(float x) {
  return __builtin_bit_cast(
      float, __builtin_amdgcn_update_dpp(0, __builtin_bit_cast(int, x), CTRL,
                                         0xF, 0xF, true));
}

__device__ __forceinline__ void load_a2(const float* __restrict__ im1b,
                                        v2f a2[4][2]) {
  const float4 r0 = *reinterpret_cast<const float4*>(im1b + 0 * WW);
  const float4 r1 = *reinterpret_cast<const float4*>(im1b + 1 * WW);
  const float4 r2 = *reinterpret_cast<const float4*>(im1b + 2 * WW);
  const float4 r3 = *reinterpret_cast<const float4*>(im1b + 3 * WW);
  a2[0][0] = (v2f){r0.x, r1.x}; a2[1][0] = (v2f){r0.y, r1.y};
  a2[2][0] = (v2f){r0.z, r1.z}; a2[3][0] = (v2f){r0.w, r1.w};
  a2[0][1] = (v2f){r2.x, r3.x}; a2[1][1] = (v2f){r2.y, r3.y};
  a2[2][1] = (v2f){r2.z, r3.z}; a2[3][1] = (v2f){r2.w, r3.w};
}

// Phases 1+2 + reduces + write for one 4x4 output block (R7-verbatim math).
__device__ __forceinline__ void tile_compute(const v2f a2[4][2],
                                             const v2f w2[10][2],
                                             float* __restrict__ outb,
                                             const int lane, const int by,
                                             const int bx) {
  // Phase 1: 7 SADs (packed).
  float sad[7];
#pragma unroll
  for (int t = 0; t < 7; ++t) {
    v2f acc = (v2f){0.f, 0.f};
#pragma unroll
    for (int c = 0; c < 4; ++c) {
#pragma unroll
      for (int rp = 0; rp < 2; ++rp) {
        const v2f d = a2[c][rp] - w2[t + c][rp];
        acc += __builtin_elementwise_max(d, -d);
      }
    }
    sad[t] = acc.x + acc.y;
  }
  if (lane == 63) {
#pragma unroll
    for (int t = 0; t < 7; ++t) sad[t] = 3.0e38f;
  }

  // Exact global min SAD: lane-local tree, then xor-butterfly
  // {1,2 DPP, 4 shfl, 8 DPP, 16,32 shfl}.
  float m;
  {
    const float m0 = fminf(sad[0], sad[1]);
    const float m1 = fminf(sad[2], sad[3]);
    const float m2 = fminf(sad[4], sad[5]);
    m = fminf(fminf(m0, m1), fminf(m2, sad[6]));
  }
  m = fminf(m, dppf<0xB1>(m));
  m = fminf(m, dppf<0x4E>(m));
  m = fminf(m, __shfl_xor(m, 4, 64));
  m = fminf(m, dppf<0x128>(m));
  m = fminf(m, __shfl_xor(m, 16, 64));
  m = fminf(m, __shfl_xor(m, 32, 64));

  // Phase 2: weights + packed FMA accumulation.
  // logit = -6.25*sad; exp2 const cc = 6.25*log2(e).
  const float cc = 9.016844005556021f;
  const float cm = cc * m;
  float l = 0.f;
  v2f o2[4][2];
#pragma unroll
  for (int c = 0; c < 4; ++c)
#pragma unroll
    for (int rp = 0; rp < 2; ++rp) o2[c][rp] = (v2f){0.f, 0.f};
#pragma unroll
  for (int t = 0; t < 7; ++t) {
    const float p = __builtin_amdgcn_exp2f(__builtin_fmaf(-cc, sad[t], cm));
    l += p;
    const v2f pv = (v2f){p, p};
#pragma unroll
    for (int c = 0; c < 4; ++c)
#pragma unroll
      for (int rp = 0; rp < 2; ++rp)
        o2[c][rp] += pv * w2[t + c][rp];   // v_pk_fma_f32
  }

  // Unpack to o[dy*4+dx]; halving in stage order {1,2,8,4}, butterflies
  // {16,32}. Wide stages DPP, narrow shfl (R7-proven).
  float o[16];
#pragma unroll
  for (int c = 0; c < 4; ++c)
#pragma unroll
    for (int rp = 0; rp < 2; ++rp) {
      o[(2 * rp + 0) * 4 + c] = o2[c][rp].x;
      o[(2 * rp + 1) * 4 + c] = o2[c][rp].y;
    }

  float r8[8];
  {
    const bool t1 = (lane & 1) != 0;     // d=1 (quad_perm xor1)
#pragma unroll
    for (int q = 0; q < 8; ++q) {
      const float send = t1 ? o[q] : o[q + 8];
      const float recv = dppf<0xB1>(send);
      r8[q] = (t1 ? o[q + 8] : o[q]) + recv;
    }
  }
  float r4[4];
  {
    const bool t2 = (lane & 2) != 0;     // d=2 (quad_perm xor2)
#pragma unroll
    for (int q = 0; q < 4; ++q) {
      const float send = t2 ? r8[q] : r8[q + 4];
      const float recv = dppf<0x4E>(send);
      r4[q] = (t2 ? r8[q + 4] : r8[q]) + recv;
    }
  }
  float r2[2];
  {
    const bool t8 = (lane & 8) != 0;     // d=8 (ror8 == xor8 in 16-ring)
#pragma unroll
    for (int q = 0; q < 2; ++q) {
      const float send = t8 ? r4[q] : r4[q + 2];
      const float recv = dppf<0x128>(send);
      r2[q] = (t8 ? r4[q + 2] : r4[q]) + recv;
    }
  }
  float r1;
  {
    const bool t4 = (lane & 4) != 0;     // d=4 (shfl)
    const float send = t4 ? r2[0] : r2[1];
    const float recv = __shfl_xor(send, 4, 64);
    r1 = (t4 ? r2[1] : r2[0]) + recv;
  }
  r1 += __shfl_xor(r1, 16, 64);
  r1 += __shfl_xor(r1, 32, 64);

  // l-reduce: same xor-butterfly mix.
  l += dppf<0xB1>(l);
  l += dppf<0x4E>(l);
  l += __shfl_xor(l, 4, 64);
  l += dppf<0x128>(l);
  l += __shfl_xor(l, 16, 64);
  l += __shfl_xor(l, 32, 64);
  const float rinv = __builtin_amdgcn_rcpf(l);  // l >= 1 always

  // Ownership from stage order: dy = 2*L0 + L1, dx = 2*L3 + L2.
  if (lane < 16) {
    const int dy = ((lane & 1) << 1) | ((lane >> 1) & 1);
    const int dx = ((lane & 8) >> 2) | ((lane & 4) >> 2);
    outb[(by * 4 + dy) * WW + bx * 4 + dx] = r1 * rinv;
  }
}

__global__ __launch_bounds__(256, 4) void pred_kernel(
    const float* __restrict__ im1, const float* __restrict__ im2,
    float* __restrict__ out) {
  __shared__ __attribute__((aligned(16))) float win2[LDSN];

  const int tid = threadIdx.x;
  const int T = blockIdx.x;
  const int b = T >> 9;            // 512 paired tiles per image
  const int rem = T & 511;
  const int tr = rem >> 4;         // tile row 0..31
  const int k = rem & 15;          // tile-pair col 0..15 (covers tc=2k,2k+1)
  const float* im2b = im2 + b * (HH * WW);
  float* outb = out + b * (HH * WW);

  const int wave = tid >> 6;
  const int lane = tid & 63;
  const int by = tr * 2 + (wave >> 1);
  const int bxA = 4 * k + (wave & 1);   // tile A block-col; tile B = +2

  // Tile A's im1 block up front (overlaps staging).
  v2f a2[4][2];
  const float* im1base = im1 + b * (HH * WW);
  load_a2(im1base + (by * 4) * WW + bxA * 4, a2);

  // Stage combined 28x36 zero-padded window, col-major stride 29, float2
  // granularity (gc0 even; validity pairwise since pad=10 even).
  {
    const int gr0 = tr * 8 - PAD;
    const int gc0 = 16 * k - PAD;
    if (((unsigned)(tr - 2) < 28u) & ((unsigned)(k - 1) < 14u)) {
      // interior: whole window in-bounds, no checks
      for (int e = tid; e < NR * (NCW / 2); e += 256) {
        const int r = e / (NCW / 2);
        const int c2 = e - r * (NCW / 2);
        const float2 v = *reinterpret_cast<const float2*>(
            &im2b[(gr0 + r) * WW + (gc0 + 2 * c2)]);
        win2[(2 * c2 + 0) * CSTR + r] = v.x;
        win2[(2 * c2 + 1) * CSTR + r] = v.y;
      }
    } else {
      for (int e = tid; e < NR * (NCW / 2); e += 256) {
        const int r = e / (NCW / 2);
        const int c2 = e - r * (NCW / 2);
        const int gr = gr0 + r;
        const int gc = gc0 + 2 * c2;
        float2 v = {0.f, 0.f};
        if (((unsigned)gr < HH) & ((unsigned)gc < WW))
          v = *reinterpret_cast<const float2*>(&im2b[gr * WW + gc]);
        win2[(2 * c2 + 0) * CSTR + r] = v.x;
        win2[(2 * c2 + 1) * CSTR + r] = v.y;
      }
    }
  }
  __syncthreads();

  // Lane's shift tile: shift row i (dy), shift cols j0..j0+6 (lane 63 dummy).
  const int i = lane / 3;
  const int j0 = (lane - i * 3) * 7;
  const int ir = i + (wave >> 1) * 4;
  const int jc = j0 + (wave & 1) * 4;
  const int baseIdx = (lane == 63) ? 0 : (jc * CSTR + ir);

  // Tile A: 4x10 register window (ds_read2_b32 pairs).
  v2f w2[10][2];
#pragma unroll
  for (int c = 0; c < 10; ++c) {
    const float* p = &win2[baseIdx + c * CSTR];
    w2[c][0] = (v2f){p[0], p[1]};
    w2[c][1] = (v2f){p[2], p[3]};
  }

  tile_compute(a2, w2, outb, lane, by, bxA);

  // Tile B: im1 block +8 px; window shifted +8 cols in the combined LDS.
  // Reuse w2 cols 8,9 as B's cols 0,1; read 8 fresh columns.
  load_a2(im1base + (by * 4) * WW + (bxA + 2) * 4, a2);
  w2[0][0] = w2[8][0]; w2[0][1] = w2[8][1];
  w2[1][0] = w2[9][0]; w2[1][1] = w2[9][1];
#pragma unroll
  for (int c = 2; c < 10; ++c) {
    const float* p = &win2[baseIdx + (8 + c) * CSTR];
    w2[c][0] = (v2f){p[0], p[1]};
    w2[c][1] = (v2f){p[2], p[3]};
  }

  tile_compute(a2, w2, outb, lane, by, bxA + 2);
}

extern "C" void kernel_launch(void* const* d_in, const int* in_sizes, int n_in,
                              void* d_out, int out_size, void* d_ws, size_t ws_size,
                              hipStream_t stream) {
  const float* im1 = (const float*)d_in[0];
  const float* im2 = (const float*)d_in[1];
  float* out = (float*)d_out;
  const int B = in_sizes[0] / (HH * WW);  // 2
  pred_kernel<<<B * 512, 256, 0, stream>>>(im1, im2, out);
}

// Round 7
// 62.530 us; speedup vs baseline: 1.0022x; 1.0022x over previous
//
#include <hip/hip_runtime.h>
#include <math.h>

// Inter-prediction: 21x21 search, 4x4 blocks, softmax(-100*meanAbsDiff).
// One wave per 4x4 block; WG=256 (4 waves) = 2x2 block tile.
//
// R9 = R7 structure (paired tiles of R8 reverted: serializing 2 tiles/wave
// regressed) + deferred-max softmax:
//  - Phase 2 uses the PER-LANE min ml (logits <= 0, p <= 1: safe), so it no
//    longer waits on the wave-wide m-butterfly. The butterfly (3 DPP + 3
//    swizzle, ~400cy serial) runs CONCURRENTLY; its result mg only feeds a
//    final rescale s = exp2(cc*(mg-ml)) (<=1; ==1 on winning lane -> l>=1,
//    rcp safe): l *= s, o2 *= s (1 exp + 9 pk_mul).
//  - Lane 63 (dummy): butterfly input poisoned to 3e38, contribution nulled
//    via s=0 (cndmask AFTER exp2, so inf from exp2 never propagates).
// Carried from R7: DPP xor1/xor2/xor8 + shfl 4/16/32 reduces (proven),
// o-reduce stage order {1,2,8,4,16,32} w/ remapped ownership, single-copy
// col-major stride-29 window, float2 staging + interior fast path,
// __launch_bounds__(256,4).
//
// (R9 resubmission: previous round's bench failed on container acquisition,
// kernel never ran.)

typedef float v2f __attribute__((ext_vector_type(2)));

#define HH 256
#define WW 256
#define PAD 10
#define NR 28
#define NC 28
#define CSTR 29            // odd per-column stride (floats)
#define LDSN (NC * CSTR)   // 812 floats = 3248 B

// Exact-xor lane exchange on the VALU (no LDS pipe, no lgkmcnt).
// CTRL: 0xB1 = xor1, 0x4E = xor2, 0x128 = xor8 (ROW_ROR:8 on a 16-ring).
template <int CTRL>
__device__ __forceinline__ float dppf(float x) {
  return __builtin_bit_cast(
      float, __builtin_amdgcn_update_dpp(0, __builtin_bit_cast(int, x), CTRL,
                                         0xF, 0xF, true));
}

__global__ __launch_bounds__(256, 4) void pred_kernel(
    const float* __restrict__ im1, const float* __restrict__ im2,
    float* __restrict__ out) {
  __shared__ __attribute__((aligned(16))) float win2[LDSN];

  const int tid = threadIdx.x;
  const int T = blockIdx.x;
  const int b = T >> 10;           // 1024 2x2-block tiles per image
  const int rem = T & 1023;
  const int tr = rem >> 5;
  const int tc = rem & 31;
  const float* im2b = im2 + b * (HH * WW);

  const int wave = tid >> 6;
  const int lane = tid & 63;
  const int by = tr * 2 + (wave >> 1);
  const int bx = tc * 2 + (wave & 1);

  // im1 4x4 block as row-pair v2 per column: a2[col][rp] = {row2rp, row2rp+1}
  v2f a2[4][2];
  {
    const float* im1b = im1 + b * (HH * WW) + (by * 4) * WW + bx * 4;
    const float4 r0 = *reinterpret_cast<const float4*>(im1b + 0 * WW);
    const float4 r1 = *reinterpret_cast<const float4*>(im1b + 1 * WW);
    const float4 r2 = *reinterpret_cast<const float4*>(im1b + 2 * WW);
    const float4 r3 = *reinterpret_cast<const float4*>(im1b + 3 * WW);
    a2[0][0] = (v2f){r0.x, r1.x}; a2[1][0] = (v2f){r0.y, r1.y};
    a2[2][0] = (v2f){r0.z, r1.z}; a2[3][0] = (v2f){r0.w, r1.w};
    a2[0][1] = (v2f){r2.x, r3.x}; a2[1][1] = (v2f){r2.y, r3.y};
    a2[2][1] = (v2f){r2.z, r3.z}; a2[3][1] = (v2f){r2.w, r3.w};
  }

  // Stage 28x28 zero-padded window, col-major stride 29, float2 granularity.
  {
    const int gr0 = tr * 8 - PAD;
    const int gc0 = tc * 8 - PAD;
    if (((unsigned)(tr - 2) < 28u) & ((unsigned)(tc - 2) < 28u)) {
      // interior: whole window in-bounds, no checks
      for (int e = tid; e < NR * (NC / 2); e += 256) {
        const int r = e / 14;
        const int c2 = e - r * 14;
        const float2 v = *reinterpret_cast<const float2*>(
            &im2b[(gr0 + r) * WW + (gc0 + 2 * c2)]);
        win2[(2 * c2 + 0) * CSTR + r] = v.x;
        win2[(2 * c2 + 1) * CSTR + r] = v.y;
      }
    } else {
      for (int e = tid; e < NR * (NC / 2); e += 256) {
        const int r = e / 14;
        const int c2 = e - r * 14;
        const int gr = gr0 + r;
        const int gc = gc0 + 2 * c2;
        float2 v = {0.f, 0.f};
        if (((unsigned)gr < HH) & ((unsigned)gc < WW))
          v = *reinterpret_cast<const float2*>(&im2b[gr * WW + gc]);
        win2[(2 * c2 + 0) * CSTR + r] = v.x;
        win2[(2 * c2 + 1) * CSTR + r] = v.y;
      }
    }
  }
  __syncthreads();

  // Lane's shift tile: shift row i (dy), shift cols j0..j0+6 (lane 63 dummy).
  const int i = lane / 3;
  const int j0 = (lane - i * 3) * 7;
  const int ir = i + (wave >> 1) * 4;   // window row of shift origin
  const int jc = j0 + (wave & 1) * 4;   // window col of shift origin
  const int baseIdx = (lane == 63) ? 0 : (jc * CSTR + ir);

  // 4x10 register window as row-pair v2s (compiler merges to ds_read2_b32).
  v2f w2[10][2];
#pragma unroll
  for (int c = 0; c < 10; ++c) {
    const float* p = &win2[baseIdx + c * CSTR];
    w2[c][0] = (v2f){p[0], p[1]};
    w2[c][1] = (v2f){p[2], p[3]};
  }

  // Phase 1: 7 SADs (packed). Lane 63's values are finite garbage (nulled
  // later via s=0).
  float sad[7];
#pragma unroll
  for (int t = 0; t < 7; ++t) {
    v2f acc = (v2f){0.f, 0.f};
#pragma unroll
    for (int c = 0; c < 4; ++c) {
#pragma unroll
      for (int rp = 0; rp < 2; ++rp) {
        const v2f d = a2[c][rp] - w2[t + c][rp];
        acc += __builtin_elementwise_max(d, -d);
      }
    }
    sad[t] = acc.x + acc.y;
  }

  // Per-lane min (phase-2 max-logit surrogate; exact for the winning lane).
  float ml;
  {
    const float m0 = fminf(sad[0], sad[1]);
    const float m1 = fminf(sad[2], sad[3]);
    const float m2 = fminf(sad[4], sad[5]);
    ml = fminf(fminf(m0, m1), fminf(m2, sad[6]));
  }

  // Global-min butterfly — OFF the critical path: phase 2 below does not
  // depend on mg, so the scheduler hides these 6 serial cross-lane ops
  // (3 DPP + 3 swizzle) under the exp/fma stream.
  float mg = (lane == 63) ? 3.0e38f : ml;
  mg = fminf(mg, dppf<0xB1>(mg));          // xor1
  mg = fminf(mg, dppf<0x4E>(mg));          // xor2
  mg = fminf(mg, __shfl_xor(mg, 4, 64));   // xor4
  mg = fminf(mg, dppf<0x128>(mg));         // xor8
  mg = fminf(mg, __shfl_xor(mg, 16, 64));  // xor16
  mg = fminf(mg, __shfl_xor(mg, 32, 64));  // xor32

  // Phase 2 with per-lane max: logit = -6.25*sad; cc = 6.25*log2(e).
  const float cc = 9.016844005556021f;
  const float cml = cc * ml;
  float l = 0.f;
  v2f o2[4][2];
#pragma unroll
  for (int c = 0; c < 4; ++c)
#pragma unroll
    for (int rp = 0; rp < 2; ++rp) o2[c][rp] = (v2f){0.f, 0.f};
#pragma unroll
  for (int t = 0; t < 7; ++t) {
    const float p = __builtin_amdgcn_exp2f(__builtin_fmaf(-cc, sad[t], cml));
    l += p;
    const v2f pv = (v2f){p, p};
#pragma unroll
    for (int c = 0; c < 4; ++c)
#pragma unroll
      for (int rp = 0; rp < 2; ++rp)
        o2[c][rp] += pv * w2[t + c][rp];   // v_pk_fma_f32
  }

  // Rescale to the global max-logit: s <= 1, s == 1 on the winning lane
  // (so l >= 1 after the l-reduce). Lane 63 nulled AFTER exp2 (cndmask),
  // so a possible inf from exp2 never propagates.
  float s = __builtin_amdgcn_exp2f(cc * (mg - ml));
  if (lane == 63) s = 0.f;
  l *= s;
  {
    const v2f sv = (v2f){s, s};
#pragma unroll
    for (int c = 0; c < 4; ++c)
#pragma unroll
      for (int rp = 0; rp < 2; ++rp) o2[c][rp] *= sv;
  }

  // Unpack to o[dy*4+dx]; halving in stage order {1,2,8,4}, butterflies
  // {16,32}. Wide stages DPP, narrow shfl (R7-proven).
  float o[16];
#pragma unroll
  for (int c = 0; c < 4; ++c)
#pragma unroll
    for (int rp = 0; rp < 2; ++rp) {
      o[(2 * rp + 0) * 4 + c] = o2[c][rp].x;
      o[(2 * rp + 1) * 4 + c] = o2[c][rp].y;
    }

  float r8[8];
  {
    const bool t1 = (lane & 1) != 0;     // d=1 (quad_perm xor1)
#pragma unroll
    for (int q = 0; q < 8; ++q) {
      const float send = t1 ? o[q] : o[q + 8];
      const float recv = dppf<0xB1>(send);
      r8[q] = (t1 ? o[q + 8] : o[q]) + recv;
    }
  }
  float r4[4];
  {
    const bool t2 = (lane & 2) != 0;     // d=2 (quad_perm xor2)
#pragma unroll
    for (int q = 0; q < 4; ++q) {
      const float send = t2 ? r8[q] : r8[q + 4];
      const float recv = dppf<0x4E>(send);
      r4[q] = (t2 ? r8[q + 4] : r8[q]) + recv;
    }
  }
  float r2[2];
  {
    const bool t8 = (lane & 8) != 0;     // d=8 (ror8 == xor8 in 16-ring)
#pragma unroll
    for (int q = 0; q < 2; ++q) {
      const float send = t8 ? r4[q] : r4[q + 2];
      const float recv = dppf<0x128>(send);
      r2[q] = (t8 ? r4[q + 2] : r4[q]) + recv;
    }
  }
  float r1;
  {
    const bool t4 = (lane & 4) != 0;     // d=4 (shfl)
    const float send = t4 ? r2[0] : r2[1];
    const float recv = __shfl_xor(send, 4, 64);
    r1 = (t4 ? r2[1] : r2[0]) + recv;
  }
  r1 += __shfl_xor(r1, 16, 64);
  r1 += __shfl_xor(r1, 32, 64);

  // l-reduce: same xor-butterfly mix.
  l += dppf<0xB1>(l);
  l += dppf<0x4E>(l);
  l += __shfl_xor(l, 4, 64);
  l += dppf<0x128>(l);
  l += __shfl_xor(l, 16, 64);
  l += __shfl_xor(l, 32, 64);
  const float rinv = __builtin_amdgcn_rcpf(l);  // l >= 1 always

  // Ownership from stage order: dy = 2*L0 + L1, dx = 2*L3 + L2.
  if (lane < 16) {
    const int dy = ((lane & 1) << 1) | ((lane >> 1) & 1);
    const int dx = ((lane & 8) >> 2) | ((lane & 4) >> 2);
    out[b * (HH * WW) + (by * 4 + dy) * WW + bx * 4 + dx] = r1 * rinv;
  }
}

extern "C" void kernel_launch(void* const* d_in, const int* in_sizes, int n_in,
                              void* d_out, int out_size, void* d_ws, size_t ws_size,
                              hipStream_t stream) {
  const float* im1 = (const float*)d_in[0];
  const float* im2 = (const float*)d_in[1];
  float* out = (float*)d_out;
  const int B = in_sizes[0] / (HH * WW);  // 2
  pred_kernel<<<B * 1024, 256, 0, stream>>>(im1, im2, out);
}